// Round 1
// baseline (221.755 us; speedup 1.0000x reference)
//
#include <hip/hip_runtime.h>
#include <math.h>

#define BB 16
#define CC 256
#define HALF 128
#define HW 6400
#define OCH 127   // HALF-1
#define ICH 129   // HALF+1
#define BN_EPS 1e-5f

// ---------------- kernel 1: per-(b,c) spatial mean ----------------
__global__ __launch_bounds__(256) void k_means(const float* __restrict__ x1,
                                               float* __restrict__ means) {
    int bc = blockIdx.x;                       // 0 .. B*C-1
    const float* p = x1 + (size_t)bc * HW;
    float s = 0.f;
    for (int i = threadIdx.x; i < HW; i += 256) s += p[i];
    #pragma unroll
    for (int off = 32; off; off >>= 1) s += __shfl_down(s, off, 64);
    __shared__ float red[4];
    int lane = threadIdx.x & 63, w = threadIdx.x >> 6;
    if (lane == 0) red[w] = s;
    __syncthreads();
    if (threadIdx.x == 0) {
        float t = red[0] + red[1] + red[2] + red[3];
        means[bc] = t * (1.0f / HW);
    }
}

// ---------------- kernel 2: ECA conv + sigmoid + top-k selection ----------------
__global__ __launch_bounds__(256) void k_select(const float* __restrict__ means,
                                                const float* __restrict__ eca_w,
                                                int* __restrict__ posidx,
                                                int* __restrict__ negidx) {
    int b = blockIdx.x;
    int c = threadIdx.x;
    __shared__ float m[CC];
    __shared__ float s[CC];
    __shared__ int flag[CC];
    m[c] = means[b * CC + c];
    __syncthreads();
    float y = 0.f;
    #pragma unroll
    for (int k = 0; k < 5; k++) {
        int cc = c + k - 2;
        float mv = (cc >= 0 && cc < CC) ? m[cc] : 0.f;
        y += eca_w[k] * mv;
    }
    float sc = 1.f / (1.f + expf(-y));
    s[c] = sc;
    __syncthreads();
    // rank with lax.top_k tie-break: lower index wins ties
    int rank = 0;
    for (int j = 0; j < CC; j++) {
        float sj = s[j];
        rank += (sj > sc) || (sj == sc && j < c);
    }
    int ispos = (rank < HALF) ? 1 : 0;
    flag[c] = ispos;
    __syncthreads();
    int pre = 0;
    for (int j = 0; j < c; j++) pre += flag[j];
    if (ispos) posidx[b * HALF + pre] = c;        // ascending channel order
    else       negidx[b * HALF + (c - pre)] = c;  // ascending channel order
}

// ---------------- kernel 3: transpose conv_w to column-major (pad 128) ----------------
__global__ __launch_bounds__(256) void k_wt(const float* __restrict__ cw,
                                            float* __restrict__ WT) {
    for (int idx = threadIdx.x + blockIdx.x * 256; idx < ICH * OCH; idx += 256 * gridDim.x) {
        int i = idx / OCH, o = idx % OCH;
        WT[i * 128 + o] = cw[o * ICH + i];
    }
}

// ---------------- kernel 4: main fused kernel, thread-per-pixel ----------------
__global__ __launch_bounds__(64) void k_main(const float* __restrict__ x0,
                                             const float* __restrict__ x1,
                                             const float* __restrict__ WT,
                                             const int* __restrict__ posidx,
                                             const int* __restrict__ negidx,
                                             const float* __restrict__ bn_gamma,
                                             const float* __restrict__ bn_beta,
                                             const float* __restrict__ bn_mean,
                                             const float* __restrict__ bn_var,
                                             float* __restrict__ out) {
    int blk = blockIdx.x;              // 16 * 100
    int b = blk / (HW / 64);
    int tile = blk % (HW / 64);
    int p = tile * 64 + threadIdx.x;   // pixel index

    const float* x1b = x1 + (size_t)b * CC * HW;
    const float* x0b = x0 + (size_t)b * CC * HW;
    float* outb = out + (size_t)b * 2 * CC * HW;

    float z[OCH];
    #pragma unroll
    for (int o = 0; o < OCH; o++) z[o] = 0.f;

    const int* pidx = posidx + b * HALF;
    const int* nidx = negidx + b * HALF;

    // pos channels: gather, fused first-half output store, matmul accumulate
    for (int j = 0; j < HALF; j++) {
        int cj = __builtin_amdgcn_readfirstlane(pidx[j]);
        float v = x1b[(size_t)cj * HW + p];   // tmp1[j]
        float d = x1b[(size_t)j * HW + p];    // direct channel j
        outb[(size_t)(CC + j) * HW + p] = d + v;
        const float* wc = WT + j * 128;
        #pragma unroll
        for (int o = 0; o < OCH; o++) z[o] += wc[o] * v;
    }

    // neg channels: running sum -> mean
    float sneg = 0.f;
    for (int j = 0; j < HALF; j++) {
        int cj = __builtin_amdgcn_readfirstlane(nidx[j]);
        sneg += x1b[(size_t)cj * HW + p];
    }
    float mn = sneg * (1.0f / HALF);

    {   // tmp1[128] = mean contribution
        const float* wc = WT + 128 * 128;
        #pragma unroll
        for (int o = 0; o < OCH; o++) z[o] += wc[o] * mn;
    }
    outb[(size_t)(CC + HALF) * HW + p] = x1b[(size_t)HALF * HW + p] + mn;

    // BN + leaky relu + residual add (channels 385..511)
    #pragma unroll
    for (int o = 0; o < OCH; o++) {
        float scale = bn_gamma[o] / sqrtf(bn_var[o] + BN_EPS);
        float zz = (z[o] - bn_mean[o]) * scale + bn_beta[o];
        float t2 = zz > 0.f ? zz : 0.1f * zz;
        outb[(size_t)(CC + HALF + 1 + o) * HW + p] = x1b[(size_t)(HALF + 1 + o) * HW + p] + t2;
    }

    // copy x0 into first half (channels 0..255)
    #pragma unroll 4
    for (int c = 0; c < CC; c++) {
        outb[(size_t)c * HW + p] = x0b[(size_t)c * HW + p];
    }
}

extern "C" void kernel_launch(void* const* d_in, const int* in_sizes, int n_in,
                              void* d_out, int out_size, void* d_ws, size_t ws_size,
                              hipStream_t stream) {
    const float* x0      = (const float*)d_in[0];
    const float* x1      = (const float*)d_in[1];
    const float* eca_w   = (const float*)d_in[2];
    const float* conv_w  = (const float*)d_in[3];
    const float* bn_gamma= (const float*)d_in[4];
    const float* bn_beta = (const float*)d_in[5];
    const float* bn_mean = (const float*)d_in[6];
    const float* bn_var  = (const float*)d_in[7];
    float* out = (float*)d_out;

    float* ws    = (float*)d_ws;
    float* means = ws;                       // 4096 f32
    int*   posidx = (int*)(ws + 4096);       // 2048 i32
    int*   negidx = posidx + 2048;           // 2048 i32
    float* WT    = ws + 4096 + 2048 + 2048;  // 129*128 f32

    k_means<<<BB * CC, 256, 0, stream>>>(x1, means);
    k_select<<<BB, 256, 0, stream>>>(means, eca_w, posidx, negidx);
    k_wt<<<64, 256, 0, stream>>>(conv_w, WT);
    k_main<<<BB * (HW / 64), 64, 0, stream>>>(x0, x1, WT, posidx, negidx,
                                              bn_gamma, bn_beta, bn_mean, bn_var, out);
}

// Round 2
// 170.308 us; speedup vs baseline: 1.3021x; 1.3021x over previous
//
#include <hip/hip_runtime.h>
#include <math.h>

#define BB 16
#define CC 256
#define HALF 128
#define HW 6400
#define OCH 127   // HALF-1
#define ICH 129   // HALF+1
#define BN_EPS 1e-5f
#define PIX 64    // pixels per block
#define NW 4      // waves per block

// ---------------- kernel 1: per-(b,c) spatial mean (float4) ----------------
__global__ __launch_bounds__(256) void k_means(const float* __restrict__ x1,
                                               float* __restrict__ means) {
    int bc = blockIdx.x;                       // 0 .. B*C-1
    const float4* p = (const float4*)(x1 + (size_t)bc * HW);
    float s = 0.f;
    for (int i = threadIdx.x; i < HW / 4; i += 256) {
        float4 v = p[i];
        s += (v.x + v.y) + (v.z + v.w);
    }
    #pragma unroll
    for (int off = 32; off; off >>= 1) s += __shfl_down(s, off, 64);
    __shared__ float red[4];
    int lane = threadIdx.x & 63, w = threadIdx.x >> 6;
    if (lane == 0) red[w] = s;
    __syncthreads();
    if (threadIdx.x == 0) {
        float t = red[0] + red[1] + red[2] + red[3];
        means[bc] = t * (1.0f / HW);
    }
}

// ---------------- kernel 2: ECA conv + sigmoid + top-k selection ----------------
__global__ __launch_bounds__(256) void k_select(const float* __restrict__ means,
                                                const float* __restrict__ eca_w,
                                                int* __restrict__ posidx,
                                                int* __restrict__ negidx) {
    int b = blockIdx.x;
    int c = threadIdx.x;
    __shared__ float m[CC];
    __shared__ float s[CC];
    __shared__ int flag[CC];
    m[c] = means[b * CC + c];
    __syncthreads();
    float y = 0.f;
    #pragma unroll
    for (int k = 0; k < 5; k++) {
        int cc = c + k - 2;
        float mv = (cc >= 0 && cc < CC) ? m[cc] : 0.f;
        y += eca_w[k] * mv;
    }
    float sc = 1.f / (1.f + expf(-y));
    s[c] = sc;
    __syncthreads();
    // rank with lax.top_k tie-break: lower index wins ties
    int rank = 0;
    for (int j = 0; j < CC; j++) {
        float sj = s[j];
        rank += (sj > sc) || (sj == sc && j < c);
    }
    int ispos = (rank < HALF) ? 1 : 0;
    flag[c] = ispos;
    __syncthreads();
    int pre = 0;
    for (int j = 0; j < c; j++) pre += flag[j];
    if (ispos) posidx[b * HALF + pre] = c;        // ascending channel order
    else       negidx[b * HALF + (c - pre)] = c;  // ascending channel order
}

// ---------------- kernel 3: transpose conv_w to column-major (pad 128, zero tail) --
__global__ __launch_bounds__(256) void k_wt(const float* __restrict__ cw,
                                            float* __restrict__ WT) {
    for (int idx = threadIdx.x + blockIdx.x * 256; idx < ICH * 128; idx += 256 * gridDim.x) {
        int i = idx / 128, o = idx % 128;
        WT[idx] = (o < OCH) ? cw[o * ICH + i] : 0.f;
    }
}

// ---------------- kernel 4: main fused kernel ----------------
// block = 256 threads = 4 waves; 64 pixels per block; wave w owns o in [32w,32w+32)
__global__ __launch_bounds__(256) void k_main(const float* __restrict__ x0,
                                              const float* __restrict__ x1,
                                              const float* __restrict__ WT,
                                              const int* __restrict__ posidx,
                                              const int* __restrict__ negidx,
                                              const float* __restrict__ bn_gamma,
                                              const float* __restrict__ bn_beta,
                                              const float* __restrict__ bn_mean,
                                              const float* __restrict__ bn_var,
                                              float* __restrict__ out) {
    int blk = blockIdx.x;              // 16 * 100
    int b = blk / (HW / PIX);
    int tile = blk % (HW / PIX);
    int p0 = tile * PIX;
    int tid = threadIdx.x;
    int w = tid >> 6;
    int lane = tid & 63;
    int p = p0 + lane;                 // this thread's pixel

    __shared__ float t1[ICH * PIX];    // tmp1 staged, stride 64
    __shared__ float snegP[NW][PIX];

    const float* x1b = x1 + (size_t)b * CC * HW;
    const float* x0b = x0 + (size_t)b * CC * HW;
    float* outb = out + (size_t)b * 2 * CC * HW;
    const int* pidx = posidx + b * HALF;
    const int* nidx = negidx + b * HALF;

    // ---- load phase: wave w handles j = jj*4 + w ----
    float sneg = 0.f;
    for (int jj = 0; jj < HALF / NW; jj++) {
        int j = jj * NW + w;
        int cj = pidx[j];                              // wave-uniform
        float v = x1b[(size_t)cj * HW + p];            // tmp1[j]
        float d = x1b[(size_t)j * HW + p];             // direct channel j
        outb[(size_t)(CC + j) * HW + p] = d + v;
        t1[j * PIX + lane] = v;
        int cn = nidx[j];
        sneg += x1b[(size_t)cn * HW + p];
    }
    snegP[w][lane] = sneg;
    __syncthreads();
    if (w == 0) {
        float mn = (snegP[0][lane] + snegP[1][lane] + snegP[2][lane] + snegP[3][lane])
                   * (1.0f / HALF);
        t1[HALF * PIX + lane] = mn;
        outb[(size_t)(CC + HALF) * HW + p] = x1b[(size_t)HALF * HW + p] + mn;
    }
    __syncthreads();

    // ---- compute phase: z[32] accumulator over 129 LDS rows ----
    int sg = __builtin_amdgcn_readfirstlane(w);        // scalar o-group
    const float* wbase = WT + sg * 32;
    float z[32];
    #pragma unroll
    for (int k = 0; k < 32; k++) z[k] = 0.f;
    for (int i = 0; i < ICH; i++) {
        float v = t1[i * PIX + lane];
        const float* wc = wbase + i * 128;             // uniform address -> s_load
        #pragma unroll
        for (int k = 0; k < 32; k++) z[k] += wc[k] * v;
    }

    // ---- epilogue: BN + leaky + residual for o = sg*32 + k ----
    #pragma unroll
    for (int k = 0; k < 32; k++) {
        int o = sg * 32 + k;
        if (o < OCH) {
            float scale = bn_gamma[o] * rsqrtf(bn_var[o] + BN_EPS);
            float zz = (z[k] - bn_mean[o]) * scale + bn_beta[o];
            float t2 = zz > 0.f ? zz : 0.1f * zz;
            outb[(size_t)(CC + HALF + 1 + o) * HW + p] =
                x1b[(size_t)(HALF + 1 + o) * HW + p] + t2;
        }
    }

    // ---- x0 copy (channels 0..255), float4 ----
    {
        int q = tid & 15;                 // float4 index within 64-pixel stripe
        int cb = tid >> 4;                // 0..15
        #pragma unroll 4
        for (int m = 0; m < 16; m++) {
            int c = m * 16 + cb;
            const float4* src = (const float4*)(x0b + (size_t)c * HW + p0);
            float4* dst = (float4*)(outb + (size_t)c * HW + p0);
            dst[q] = src[q];
        }
    }
}

extern "C" void kernel_launch(void* const* d_in, const int* in_sizes, int n_in,
                              void* d_out, int out_size, void* d_ws, size_t ws_size,
                              hipStream_t stream) {
    const float* x0      = (const float*)d_in[0];
    const float* x1      = (const float*)d_in[1];
    const float* eca_w   = (const float*)d_in[2];
    const float* conv_w  = (const float*)d_in[3];
    const float* bn_gamma= (const float*)d_in[4];
    const float* bn_beta = (const float*)d_in[5];
    const float* bn_mean = (const float*)d_in[6];
    const float* bn_var  = (const float*)d_in[7];
    float* out = (float*)d_out;

    float* ws    = (float*)d_ws;
    float* means = ws;                       // 4096 f32
    int*   posidx = (int*)(ws + 4096);       // 2048 i32
    int*   negidx = posidx + 2048;           // 2048 i32
    float* WT    = ws + 4096 + 2048 + 2048;  // 129*128 f32

    k_means<<<BB * CC, 256, 0, stream>>>(x1, means);
    k_select<<<BB, 256, 0, stream>>>(means, eca_w, posidx, negidx);
    k_wt<<<65, 256, 0, stream>>>(conv_w, WT);
    k_main<<<BB * (HW / PIX), 256, 0, stream>>>(x0, x1, WT, posidx, negidx,
                                                bn_gamma, bn_beta, bn_mean, bn_var, out);
}